// Round 1
// baseline (742.701 us; speedup 1.0000x reference)
//
#include <hip/hip_runtime.h>
#include <math.h>

#define N_NODES 100000
#define N_EDGES 1600000
#define C 64
#define OUTC 8

// ---------- CSR build ----------
__global__ __launch_bounds__(256) void hist_k(const int* __restrict__ dst, int* __restrict__ deg, int ne) {
    int e = blockIdx.x * 256 + threadIdx.x;
    if (e < ne) atomicAdd(&deg[dst[e]], 1);
}

// single-block exclusive scan over N_NODES degree counts
__global__ __launch_bounds__(1024) void scan_k(const int* __restrict__ deg, int* __restrict__ rowptr, int n) {
    __shared__ int part[1024];
    const int ITEMS = 98;  // 1024*98 = 100352 >= 100000
    int t = threadIdx.x;
    int base = t * ITEMS;
    int s = 0;
    for (int i = 0; i < ITEMS; i++) { int idx = base + i; if (idx < n) s += deg[idx]; }
    part[t] = s;
    __syncthreads();
    for (int off = 1; off < 1024; off <<= 1) {
        int v = (t >= off) ? part[t - off] : 0;
        __syncthreads();
        part[t] += v;
        __syncthreads();
    }
    int run = part[t] - s;  // exclusive prefix for this thread's chunk
    for (int i = 0; i < ITEMS; i++) {
        int idx = base + i;
        if (idx < n) { rowptr[idx] = run; run += deg[idx]; }
    }
    if (t == 0) rowptr[n] = part[1023];
}

__global__ __launch_bounds__(256) void copy_k(const int* __restrict__ a, int* __restrict__ b, int n) {
    int i = blockIdx.x * 256 + threadIdx.x;
    if (i < n) b[i] = a[i];
}

__global__ __launch_bounds__(256) void fill_k(const int* __restrict__ src, const int* __restrict__ dst,
                                              int* cur, int* __restrict__ ssrc, int ne) {
    int e = blockIdx.x * 256 + threadIdx.x;
    if (e < ne) {
        int d = dst[e];
        int p = atomicAdd(&cur[d], 1);
        ssrc[p] = src[e];
    }
}

// ---------- aggregation: t[i] = feat[i] + sum_{j->i} feat[j], wave per node ----------
__global__ __launch_bounds__(256) void gather_k(const float* __restrict__ feat,
                                                const int* __restrict__ rowptr,
                                                const int* __restrict__ ssrc,
                                                float* __restrict__ tout, int n) {
    int lane = threadIdx.x & 63;
    int wid = blockIdx.x * 4 + (threadIdx.x >> 6);
    if (wid >= n) return;
    int beg = rowptr[wid], end = rowptr[wid + 1];
    float acc = feat[wid * C + lane];  // fused + x_i
    int e = beg;
    for (; e + 4 <= end; e += 4) {  // 4 independent loads in flight
        int s0 = ssrc[e], s1 = ssrc[e + 1], s2 = ssrc[e + 2], s3 = ssrc[e + 3];
        float v0 = feat[s0 * C + lane];
        float v1 = feat[s1 * C + lane];
        float v2 = feat[s2 * C + lane];
        float v3 = feat[s3 * C + lane];
        acc += (v0 + v1) + (v2 + v3);
    }
    for (; e < end; e++) acc += feat[ssrc[e] * C + lane];
    tout[wid * C + lane] = acc;
}

// ---------- 64->64->64 MLP, wave per node, weight columns in VGPRs ----------
__global__ __launch_bounds__(256) void mlp64_k(const float* __restrict__ tin,
                                               float* __restrict__ zout,
                                               const float* __restrict__ W1, const float* __restrict__ b1,
                                               const float* __restrict__ W2, const float* __restrict__ b2,
                                               int n, int relu_out) {
    int lane = threadIdx.x & 63;
    float w1c[64], w2c[64];
#pragma unroll
    for (int k = 0; k < 64; k++) w1c[k] = W1[k * 64 + lane];
#pragma unroll
    for (int k = 0; k < 64; k++) w2c[k] = W2[k * 64 + lane];
    float b1l = b1[lane], b2l = b2[lane];
    int wid = blockIdx.x * 4 + (threadIdx.x >> 6);
    int nw = gridDim.x * 4;
    for (int nd = wid; nd < n; nd += nw) {
        float tv = tin[nd * C + lane];
        float h = b1l;
#pragma unroll
        for (int k = 0; k < 64; k++) {
            float tk = __uint_as_float(__builtin_amdgcn_readlane(__float_as_uint(tv), k));
            h = fmaf(tk, w1c[k], h);
        }
        h = fmaxf(h, 0.f);
        float y = b2l;
#pragma unroll
        for (int k = 0; k < 64; k++) {
            float hk = __uint_as_float(__builtin_amdgcn_readlane(__float_as_uint(h), k));
            y = fmaf(hk, w2c[k], y);
        }
        if (relu_out) y = fmaxf(y, 0.f);
        zout[nd * C + lane] = y;
    }
}

// ---------- final 64->8->8 MLP + log_softmax, wave per node ----------
__global__ __launch_bounds__(256) void final_k(const float* __restrict__ tin,
                                               float* __restrict__ out,
                                               const float* __restrict__ W1, const float* __restrict__ b1,
                                               const float* __restrict__ W2, const float* __restrict__ b2,
                                               int n) {
    int lane = threadIdx.x & 63;
    int j = lane & 7;       // output channel
    int g = lane >> 3;      // k-slice group
    float w1r[8], w2r[8];
#pragma unroll
    for (int i = 0; i < 8; i++) w1r[i] = W1[(g * 8 + i) * OUTC + j];
#pragma unroll
    for (int i = 0; i < 8; i++) w2r[i] = W2[i * OUTC + j];
    float b1j = b1[j], b2j = b2[j];
    int wid = blockIdx.x * 4 + (threadIdx.x >> 6);
    int nw = gridDim.x * 4;
    for (int nd = wid; nd < n; nd += nw) {
        float tv = tin[nd * C + lane];  // lane holds channel `lane`
        float h = 0.f;
#pragma unroll
        for (int i = 0; i < 8; i++) {
            float tk = __shfl(tv, g * 8 + i, 64);  // channels of own k-slice
            h = fmaf(tk, w1r[i], h);
        }
        // reduce partials across the 8 k-slice groups (same j)
        h += __shfl_xor(h, 8, 64);
        h += __shfl_xor(h, 16, 64);
        h += __shfl_xor(h, 32, 64);
        h += b1j;
        h = fmaxf(h, 0.f);
        float y = b2j;
#pragma unroll
        for (int k = 0; k < 8; k++) {
            float hk = __shfl(h, (lane & ~7) + k, 64);
            y = fmaf(hk, w2r[k], y);
        }
        // log_softmax over the 8 channels within each group
        float m = y;
        m = fmaxf(m, __shfl_xor(m, 1, 64));
        m = fmaxf(m, __shfl_xor(m, 2, 64));
        m = fmaxf(m, __shfl_xor(m, 4, 64));
        float ex = expf(y - m);
        float ssum = ex;
        ssum += __shfl_xor(ssum, 1, 64);
        ssum += __shfl_xor(ssum, 2, 64);
        ssum += __shfl_xor(ssum, 4, 64);
        float res = (y - m) - logf(ssum);
        if (lane < 8) out[nd * OUTC + lane] = res;  // group 0 writes
    }
}

extern "C" void kernel_launch(void* const* d_in, const int* in_sizes, int n_in,
                              void* d_out, int out_size, void* d_ws, size_t ws_size,
                              hipStream_t stream) {
    const float* x = (const float*)d_in[0];
    const int* ei = (const int*)d_in[1];
    // d_in[2] = edge_attr, unused by reference
    const float* l0w1 = (const float*)d_in[3],  *l0b1 = (const float*)d_in[4];
    const float* l0w2 = (const float*)d_in[5],  *l0b2 = (const float*)d_in[6];
    const float* l1w1 = (const float*)d_in[7],  *l1b1 = (const float*)d_in[8];
    const float* l1w2 = (const float*)d_in[9],  *l1b2 = (const float*)d_in[10];
    const float* l2w1 = (const float*)d_in[11], *l2b1 = (const float*)d_in[12];
    const float* l2w2 = (const float*)d_in[13], *l2b2 = (const float*)d_in[14];
    float* out = (float*)d_out;
    const int* src = ei;
    const int* dst = ei + N_EDGES;

    char* ws = (char*)d_ws;
    size_t off = 0;
    auto carve = [&](size_t bytes) -> void* {
        void* p = ws + off;
        off += (bytes + 255) & ~(size_t)255;
        return p;
    };
    int* deg    = (int*)carve((size_t)N_NODES * 4);
    int* rowptr = (int*)carve((size_t)(N_NODES + 1) * 4);
    int* cur    = (int*)carve((size_t)N_NODES * 4);
    int* ssrc   = (int*)carve((size_t)N_EDGES * 4);
    float* tb   = (float*)carve((size_t)N_NODES * C * 4);
    float* zb   = (float*)carve((size_t)N_NODES * C * 4);
    (void)ws_size;

    // CSR build (per call; deterministic counts, bucket order may permute -> FP wobble only)
    hipMemsetAsync(deg, 0, (size_t)N_NODES * 4, stream);
    hist_k<<<(N_EDGES + 255) / 256, 256, 0, stream>>>(dst, deg, N_EDGES);
    scan_k<<<1, 1024, 0, stream>>>(deg, rowptr, N_NODES);
    copy_k<<<(N_NODES + 255) / 256, 256, 0, stream>>>(rowptr, cur, N_NODES);
    fill_k<<<(N_EDGES + 255) / 256, 256, 0, stream>>>(src, dst, cur, ssrc, N_EDGES);

    int gblocks = (N_NODES + 3) / 4;
    // layer 0
    gather_k<<<gblocks, 256, 0, stream>>>(x, rowptr, ssrc, tb, N_NODES);
    mlp64_k<<<2048, 256, 0, stream>>>(tb, zb, l0w1, l0b1, l0w2, l0b2, N_NODES, 1);
    // layer 1
    gather_k<<<gblocks, 256, 0, stream>>>(zb, rowptr, ssrc, tb, N_NODES);
    mlp64_k<<<2048, 256, 0, stream>>>(tb, zb, l1w1, l1b1, l1w2, l1b2, N_NODES, 1);
    // layer 2 + log_softmax
    gather_k<<<gblocks, 256, 0, stream>>>(zb, rowptr, ssrc, tb, N_NODES);
    final_k<<<512, 256, 0, stream>>>(tb, out, l2w1, l2b1, l2w2, l2b2, N_NODES);
}

// Round 2
// 560.399 us; speedup vs baseline: 1.3253x; 1.3253x over previous
//
#include <hip/hip_runtime.h>
#include <math.h>

#define N_NODES 100000
#define N_EDGES 1600000
#define C 64
#define OUTC 8
#define SCAN_NBLK ((N_NODES + 255) / 256)  // 391

// ---------- CSR build ----------
__global__ __launch_bounds__(256) void hist_k(const int* __restrict__ dst, int* __restrict__ deg, int ne) {
    int e = blockIdx.x * 256 + threadIdx.x;
    if (e < ne) atomicAdd(&deg[dst[e]], 1);
}

// stage 1: per-block (256-elem chunk) sums
__global__ __launch_bounds__(256) void scan_partial_k(const int* __restrict__ deg, int* __restrict__ part, int n) {
    __shared__ int red[256];
    int t = threadIdx.x;
    int i = blockIdx.x * 256 + t;
    red[t] = (i < n) ? deg[i] : 0;
    __syncthreads();
    for (int off = 128; off > 0; off >>= 1) {
        if (t < off) red[t] += red[t + off];
        __syncthreads();
    }
    if (t == 0) part[blockIdx.x] = red[0];
}

// stage 2: exclusive scan of the ~391 block partials (single small block)
__global__ __launch_bounds__(512) void scan_part2_k(int* __restrict__ part, int nb) {
    __shared__ int sm[512];
    int t = threadIdx.x;
    int v = (t < nb) ? part[t] : 0;
    sm[t] = v;
    __syncthreads();
    for (int off = 1; off < 512; off <<= 1) {
        int u = (t >= off) ? sm[t - off] : 0;
        __syncthreads();
        sm[t] += u;
        __syncthreads();
    }
    if (t < nb) part[t] = sm[t] - v;  // exclusive
}

// stage 3: per-block exclusive scan + block offset -> rowptr AND cur
__global__ __launch_bounds__(256) void scan_final_k(const int* __restrict__ deg, const int* __restrict__ part,
                                                    int* __restrict__ rowptr, int* __restrict__ cur, int n) {
    __shared__ int sm[256];
    int t = threadIdx.x;
    int i = blockIdx.x * 256 + t;
    int v = (i < n) ? deg[i] : 0;
    sm[t] = v;
    __syncthreads();
    for (int off = 1; off < 256; off <<= 1) {
        int u = (t >= off) ? sm[t - off] : 0;
        __syncthreads();
        sm[t] += u;
        __syncthreads();
    }
    int ex = sm[t] - v + part[blockIdx.x];
    if (i < n) { rowptr[i] = ex; cur[i] = ex; }
    if (i == 0) rowptr[n] = N_EDGES;  // total is a compile-time constant
}

__global__ __launch_bounds__(256) void fill_k(const int* __restrict__ src, const int* __restrict__ dst,
                                              int* cur, int* __restrict__ ssrc, int ne) {
    int e = blockIdx.x * 256 + threadIdx.x;
    if (e < ne) {
        int d = dst[e];
        int p = atomicAdd(&cur[d], 1);
        ssrc[p] = src[e];
    }
}

// ---------- aggregation: t[i] = feat[i] + sum_{j->i} feat[j], wave per node ----------
__global__ __launch_bounds__(256) void gather_k(const float* __restrict__ feat,
                                                const int* __restrict__ rowptr,
                                                const int* __restrict__ ssrc,
                                                float* __restrict__ tout, int n) {
    int lane = threadIdx.x & 63;
    int wid = blockIdx.x * 4 + (threadIdx.x >> 6);
    if (wid >= n) return;
    int beg = rowptr[wid], end = rowptr[wid + 1];
    float acc = feat[wid * C + lane];  // fused + x_i
    int e = beg;
    for (; e + 4 <= end; e += 4) {  // 4 independent loads in flight
        int s0 = ssrc[e], s1 = ssrc[e + 1], s2 = ssrc[e + 2], s3 = ssrc[e + 3];
        float v0 = feat[s0 * C + lane];
        float v1 = feat[s1 * C + lane];
        float v2 = feat[s2 * C + lane];
        float v3 = feat[s3 * C + lane];
        acc += (v0 + v1) + (v2 + v3);
    }
    for (; e < end; e++) acc += feat[ssrc[e] * C + lane];
    tout[wid * C + lane] = acc;
}

// ---------- 64->64->64 MLP, wave per node, weight columns in VGPRs ----------
__global__ __launch_bounds__(256) void mlp64_k(const float* __restrict__ tin,
                                               float* __restrict__ zout,
                                               const float* __restrict__ W1, const float* __restrict__ b1,
                                               const float* __restrict__ W2, const float* __restrict__ b2,
                                               int n, int relu_out) {
    int lane = threadIdx.x & 63;
    float w1c[64], w2c[64];
#pragma unroll
    for (int k = 0; k < 64; k++) w1c[k] = W1[k * 64 + lane];
#pragma unroll
    for (int k = 0; k < 64; k++) w2c[k] = W2[k * 64 + lane];
    float b1l = b1[lane], b2l = b2[lane];
    int wid = blockIdx.x * 4 + (threadIdx.x >> 6);
    int nw = gridDim.x * 4;
    for (int nd = wid; nd < n; nd += nw) {
        float tv = tin[nd * C + lane];
        float h = b1l;
#pragma unroll
        for (int k = 0; k < 64; k++) {
            float tk = __uint_as_float(__builtin_amdgcn_readlane(__float_as_uint(tv), k));
            h = fmaf(tk, w1c[k], h);
        }
        h = fmaxf(h, 0.f);
        float y = b2l;
#pragma unroll
        for (int k = 0; k < 64; k++) {
            float hk = __uint_as_float(__builtin_amdgcn_readlane(__float_as_uint(h), k));
            y = fmaf(hk, w2c[k], y);
        }
        if (relu_out) y = fmaxf(y, 0.f);
        zout[nd * C + lane] = y;
    }
}

// ---------- final 64->8->8 MLP + log_softmax, wave per node ----------
__global__ __launch_bounds__(256) void final_k(const float* __restrict__ tin,
                                               float* __restrict__ out,
                                               const float* __restrict__ W1, const float* __restrict__ b1,
                                               const float* __restrict__ W2, const float* __restrict__ b2,
                                               int n) {
    int lane = threadIdx.x & 63;
    int j = lane & 7;       // output channel
    int g = lane >> 3;      // k-slice group
    float w1r[8], w2r[8];
#pragma unroll
    for (int i = 0; i < 8; i++) w1r[i] = W1[(g * 8 + i) * OUTC + j];
#pragma unroll
    for (int i = 0; i < 8; i++) w2r[i] = W2[i * OUTC + j];
    float b1j = b1[j], b2j = b2[j];
    int wid = blockIdx.x * 4 + (threadIdx.x >> 6);
    int nw = gridDim.x * 4;
    for (int nd = wid; nd < n; nd += nw) {
        float tv = tin[nd * C + lane];  // lane holds channel `lane`
        float h = 0.f;
#pragma unroll
        for (int i = 0; i < 8; i++) {
            float tk = __shfl(tv, g * 8 + i, 64);  // channels of own k-slice
            h = fmaf(tk, w1r[i], h);
        }
        // reduce partials across the 8 k-slice groups (same j)
        h += __shfl_xor(h, 8, 64);
        h += __shfl_xor(h, 16, 64);
        h += __shfl_xor(h, 32, 64);
        h += b1j;
        h = fmaxf(h, 0.f);
        float y = b2j;
#pragma unroll
        for (int k = 0; k < 8; k++) {
            float hk = __shfl(h, (lane & ~7) + k, 64);
            y = fmaf(hk, w2r[k], y);
        }
        // log_softmax over the 8 channels within each group
        float m = y;
        m = fmaxf(m, __shfl_xor(m, 1, 64));
        m = fmaxf(m, __shfl_xor(m, 2, 64));
        m = fmaxf(m, __shfl_xor(m, 4, 64));
        float ex = expf(y - m);
        float ssum = ex;
        ssum += __shfl_xor(ssum, 1, 64);
        ssum += __shfl_xor(ssum, 2, 64);
        ssum += __shfl_xor(ssum, 4, 64);
        float res = (y - m) - logf(ssum);
        if (lane < 8) out[nd * OUTC + lane] = res;  // group 0 writes
    }
}

extern "C" void kernel_launch(void* const* d_in, const int* in_sizes, int n_in,
                              void* d_out, int out_size, void* d_ws, size_t ws_size,
                              hipStream_t stream) {
    const float* x = (const float*)d_in[0];
    const int* ei = (const int*)d_in[1];
    // d_in[2] = edge_attr, unused by reference
    const float* l0w1 = (const float*)d_in[3],  *l0b1 = (const float*)d_in[4];
    const float* l0w2 = (const float*)d_in[5],  *l0b2 = (const float*)d_in[6];
    const float* l1w1 = (const float*)d_in[7],  *l1b1 = (const float*)d_in[8];
    const float* l1w2 = (const float*)d_in[9],  *l1b2 = (const float*)d_in[10];
    const float* l2w1 = (const float*)d_in[11], *l2b1 = (const float*)d_in[12];
    const float* l2w2 = (const float*)d_in[13], *l2b2 = (const float*)d_in[14];
    float* out = (float*)d_out;
    const int* src = ei;
    const int* dst = ei + N_EDGES;

    char* ws = (char*)d_ws;
    size_t off = 0;
    auto carve = [&](size_t bytes) -> void* {
        void* p = ws + off;
        off += (bytes + 255) & ~(size_t)255;
        return p;
    };
    int* deg    = (int*)carve((size_t)N_NODES * 4);
    int* rowptr = (int*)carve((size_t)(N_NODES + 1) * 4);
    int* cur    = (int*)carve((size_t)N_NODES * 4);
    int* part   = (int*)carve((size_t)SCAN_NBLK * 4);
    int* ssrc   = (int*)carve((size_t)N_EDGES * 4);
    float* tb   = (float*)carve((size_t)N_NODES * C * 4);
    float* zb   = (float*)carve((size_t)N_NODES * C * 4);
    (void)ws_size;

    // CSR build (hierarchical scan; ~400KB traffic, full-grid kernels)
    hipMemsetAsync(deg, 0, (size_t)N_NODES * 4, stream);
    hist_k<<<(N_EDGES + 255) / 256, 256, 0, stream>>>(dst, deg, N_EDGES);
    scan_partial_k<<<SCAN_NBLK, 256, 0, stream>>>(deg, part, N_NODES);
    scan_part2_k<<<1, 512, 0, stream>>>(part, SCAN_NBLK);
    scan_final_k<<<SCAN_NBLK, 256, 0, stream>>>(deg, part, rowptr, cur, N_NODES);
    fill_k<<<(N_EDGES + 255) / 256, 256, 0, stream>>>(src, dst, cur, ssrc, N_EDGES);

    int gblocks = (N_NODES + 3) / 4;
    // layer 0
    gather_k<<<gblocks, 256, 0, stream>>>(x, rowptr, ssrc, tb, N_NODES);
    mlp64_k<<<2048, 256, 0, stream>>>(tb, zb, l0w1, l0b1, l0w2, l0b2, N_NODES, 1);
    // layer 1
    gather_k<<<gblocks, 256, 0, stream>>>(zb, rowptr, ssrc, tb, N_NODES);
    mlp64_k<<<2048, 256, 0, stream>>>(tb, zb, l1w1, l1b1, l1w2, l1b2, N_NODES, 1);
    // layer 2 + log_softmax
    gather_k<<<gblocks, 256, 0, stream>>>(zb, rowptr, ssrc, tb, N_NODES);
    final_k<<<512, 256, 0, stream>>>(tb, out, l2w1, l2b1, l2w2, l2b2, N_NODES);
}

// Round 3
// 507.289 us; speedup vs baseline: 1.4641x; 1.1047x over previous
//
#include <hip/hip_runtime.h>
#include <math.h>

#define N_NODES 100000
#define N_EDGES 1600000
#define C 64
#define OUTC 8
#define SCAN_NBLK ((N_NODES + 255) / 256)  // 391
#define FILL_RANGES 8
#define FILL_BLOCKS 2048  // 256 blocks per range

// ---------- CSR build ----------
__global__ __launch_bounds__(256) void hist_k(const int* __restrict__ dst, int* __restrict__ deg, int ne) {
    int e = blockIdx.x * 256 + threadIdx.x;
    if (e < ne) atomicAdd(&deg[dst[e]], 1);
}

// stage 1: per-block (256-elem chunk) sums
__global__ __launch_bounds__(256) void scan_partial_k(const int* __restrict__ deg, int* __restrict__ part, int n) {
    __shared__ int red[256];
    int t = threadIdx.x;
    int i = blockIdx.x * 256 + t;
    red[t] = (i < n) ? deg[i] : 0;
    __syncthreads();
    for (int off = 128; off > 0; off >>= 1) {
        if (t < off) red[t] += red[t + off];
        __syncthreads();
    }
    if (t == 0) part[blockIdx.x] = red[0];
}

// stage 2: exclusive scan of the ~391 block partials (single small block)
__global__ __launch_bounds__(512) void scan_part2_k(int* __restrict__ part, int nb) {
    __shared__ int sm[512];
    int t = threadIdx.x;
    int v = (t < nb) ? part[t] : 0;
    sm[t] = v;
    __syncthreads();
    for (int off = 1; off < 512; off <<= 1) {
        int u = (t >= off) ? sm[t - off] : 0;
        __syncthreads();
        sm[t] += u;
        __syncthreads();
    }
    if (t < nb) part[t] = sm[t] - v;  // exclusive
}

// stage 3: per-block exclusive scan + block offset -> rowptr AND cur
__global__ __launch_bounds__(256) void scan_final_k(const int* __restrict__ deg, const int* __restrict__ part,
                                                    int* __restrict__ rowptr, int* __restrict__ cur, int n) {
    __shared__ int sm[256];
    int t = threadIdx.x;
    int i = blockIdx.x * 256 + t;
    int v = (i < n) ? deg[i] : 0;
    sm[t] = v;
    __syncthreads();
    for (int off = 1; off < 256; off <<= 1) {
        int u = (t >= off) ? sm[t - off] : 0;
        __syncthreads();
        sm[t] += u;
        __syncthreads();
    }
    int ex = sm[t] - v + part[blockIdx.x];
    if (i < n) { rowptr[i] = ex; cur[i] = ex; }
    if (i == 0) rowptr[n] = N_EDGES;  // total is a compile-time constant
}

// dst-range-partitioned fill: range = blockIdx&7 maps round-robin to XCDs, so each
// XCD's blocks scatter-write only a ~800KB ssrc slice -> lines stay L2-resident and
// accumulate all 16 dwords before writeback (kills the 16x write amplification).
// Correctness does not depend on the XCD mapping (speed-only heuristic).
__global__ __launch_bounds__(256) void fill_ranged_k(const int* __restrict__ src, const int* __restrict__ dst,
                                                     int* cur, int* __restrict__ ssrc, int ne) {
    int range = blockIdx.x & (FILL_RANGES - 1);
    int bslot = blockIdx.x >> 3;
    const int nslot = FILL_BLOCKS / FILL_RANGES;  // 256
    int lo = range * (N_NODES / FILL_RANGES);     // 12500 per range
    int hi = lo + (N_NODES / FILL_RANGES);
    if (range == FILL_RANGES - 1) hi = N_NODES;
    for (int e = bslot * 256 + threadIdx.x; e < ne; e += nslot * 256) {
        int d = dst[e];
        if (d >= lo && d < hi) {
            int p = atomicAdd(&cur[d], 1);
            ssrc[p] = src[e];
        }
    }
}

// ---------- aggregation: t[i] = feat[i] + sum_{j->i} feat[j], wave per node ----------
__global__ __launch_bounds__(256) void gather_k(const float* __restrict__ feat,
                                                const int* __restrict__ rowptr,
                                                const int* __restrict__ ssrc,
                                                float* __restrict__ tout, int n) {
    int lane = threadIdx.x & 63;
    int wid = blockIdx.x * 4 + (threadIdx.x >> 6);
    if (wid >= n) return;
    int beg = rowptr[wid], end = rowptr[wid + 1];
    float acc = feat[wid * C + lane];  // fused + x_i
    int e = beg;
    for (; e + 4 <= end; e += 4) {  // 4 independent loads in flight
        int s0 = ssrc[e], s1 = ssrc[e + 1], s2 = ssrc[e + 2], s3 = ssrc[e + 3];
        float v0 = feat[s0 * C + lane];
        float v1 = feat[s1 * C + lane];
        float v2 = feat[s2 * C + lane];
        float v3 = feat[s3 * C + lane];
        acc += (v0 + v1) + (v2 + v3);
    }
    for (; e < end; e++) acc += feat[ssrc[e] * C + lane];
    tout[wid * C + lane] = acc;
}

// ---------- 64->64->64 MLP, wave per node, weight columns in VGPRs ----------
__global__ __launch_bounds__(256) void mlp64_k(const float* __restrict__ tin,
                                               float* __restrict__ zout,
                                               const float* __restrict__ W1, const float* __restrict__ b1,
                                               const float* __restrict__ W2, const float* __restrict__ b2,
                                               int n, int relu_out) {
    int lane = threadIdx.x & 63;
    float w1c[64], w2c[64];
#pragma unroll
    for (int k = 0; k < 64; k++) w1c[k] = W1[k * 64 + lane];
#pragma unroll
    for (int k = 0; k < 64; k++) w2c[k] = W2[k * 64 + lane];
    float b1l = b1[lane], b2l = b2[lane];
    int wid = blockIdx.x * 4 + (threadIdx.x >> 6);
    int nw = gridDim.x * 4;
    for (int nd = wid; nd < n; nd += nw) {
        float tv = tin[nd * C + lane];
        float h = b1l;
#pragma unroll
        for (int k = 0; k < 64; k++) {
            float tk = __uint_as_float(__builtin_amdgcn_readlane(__float_as_uint(tv), k));
            h = fmaf(tk, w1c[k], h);
        }
        h = fmaxf(h, 0.f);
        float y = b2l;
#pragma unroll
        for (int k = 0; k < 64; k++) {
            float hk = __uint_as_float(__builtin_amdgcn_readlane(__float_as_uint(h), k));
            y = fmaf(hk, w2c[k], y);
        }
        if (relu_out) y = fmaxf(y, 0.f);
        zout[nd * C + lane] = y;
    }
}

// ---------- final 64->8->8 MLP + log_softmax, wave per node ----------
__global__ __launch_bounds__(256) void final_k(const float* __restrict__ tin,
                                               float* __restrict__ out,
                                               const float* __restrict__ W1, const float* __restrict__ b1,
                                               const float* __restrict__ W2, const float* __restrict__ b2,
                                               int n) {
    int lane = threadIdx.x & 63;
    int j = lane & 7;       // output channel
    int g = lane >> 3;      // k-slice group
    float w1r[8], w2r[8];
#pragma unroll
    for (int i = 0; i < 8; i++) w1r[i] = W1[(g * 8 + i) * OUTC + j];
#pragma unroll
    for (int i = 0; i < 8; i++) w2r[i] = W2[i * OUTC + j];
    float b1j = b1[j], b2j = b2[j];
    int wid = blockIdx.x * 4 + (threadIdx.x >> 6);
    int nw = gridDim.x * 4;
    for (int nd = wid; nd < n; nd += nw) {
        float tv = tin[nd * C + lane];  // lane holds channel `lane`
        float h = 0.f;
#pragma unroll
        for (int i = 0; i < 8; i++) {
            float tk = __shfl(tv, g * 8 + i, 64);  // channels of own k-slice
            h = fmaf(tk, w1r[i], h);
        }
        // reduce partials across the 8 k-slice groups (same j)
        h += __shfl_xor(h, 8, 64);
        h += __shfl_xor(h, 16, 64);
        h += __shfl_xor(h, 32, 64);
        h += b1j;
        h = fmaxf(h, 0.f);
        float y = b2j;
#pragma unroll
        for (int k = 0; k < 8; k++) {
            float hk = __shfl(h, (lane & ~7) + k, 64);
            y = fmaf(hk, w2r[k], y);
        }
        // log_softmax over the 8 channels within each group
        float m = y;
        m = fmaxf(m, __shfl_xor(m, 1, 64));
        m = fmaxf(m, __shfl_xor(m, 2, 64));
        m = fmaxf(m, __shfl_xor(m, 4, 64));
        float ex = expf(y - m);
        float ssum = ex;
        ssum += __shfl_xor(ssum, 1, 64);
        ssum += __shfl_xor(ssum, 2, 64);
        ssum += __shfl_xor(ssum, 4, 64);
        float res = (y - m) - logf(ssum);
        if (lane < 8) out[nd * OUTC + lane] = res;  // group 0 writes
    }
}

extern "C" void kernel_launch(void* const* d_in, const int* in_sizes, int n_in,
                              void* d_out, int out_size, void* d_ws, size_t ws_size,
                              hipStream_t stream) {
    const float* x = (const float*)d_in[0];
    const int* ei = (const int*)d_in[1];
    // d_in[2] = edge_attr, unused by reference
    const float* l0w1 = (const float*)d_in[3],  *l0b1 = (const float*)d_in[4];
    const float* l0w2 = (const float*)d_in[5],  *l0b2 = (const float*)d_in[6];
    const float* l1w1 = (const float*)d_in[7],  *l1b1 = (const float*)d_in[8];
    const float* l1w2 = (const float*)d_in[9],  *l1b2 = (const float*)d_in[10];
    const float* l2w1 = (const float*)d_in[11], *l2b1 = (const float*)d_in[12];
    const float* l2w2 = (const float*)d_in[13], *l2b2 = (const float*)d_in[14];
    float* out = (float*)d_out;
    const int* src = ei;
    const int* dst = ei + N_EDGES;

    char* ws = (char*)d_ws;
    size_t off = 0;
    auto carve = [&](size_t bytes) -> void* {
        void* p = ws + off;
        off += (bytes + 255) & ~(size_t)255;
        return p;
    };
    int* deg    = (int*)carve((size_t)N_NODES * 4);
    int* rowptr = (int*)carve((size_t)(N_NODES + 1) * 4);
    int* cur    = (int*)carve((size_t)N_NODES * 4);
    int* part   = (int*)carve((size_t)SCAN_NBLK * 4);
    int* ssrc   = (int*)carve((size_t)N_EDGES * 4);
    float* tb   = (float*)carve((size_t)N_NODES * C * 4);
    float* zb   = (float*)carve((size_t)N_NODES * C * 4);
    (void)ws_size;

    // CSR build (hierarchical scan; ranged fill kills write amplification)
    hipMemsetAsync(deg, 0, (size_t)N_NODES * 4, stream);
    hist_k<<<(N_EDGES + 255) / 256, 256, 0, stream>>>(dst, deg, N_EDGES);
    scan_partial_k<<<SCAN_NBLK, 256, 0, stream>>>(deg, part, N_NODES);
    scan_part2_k<<<1, 512, 0, stream>>>(part, SCAN_NBLK);
    scan_final_k<<<SCAN_NBLK, 256, 0, stream>>>(deg, part, rowptr, cur, N_NODES);
    fill_ranged_k<<<FILL_BLOCKS, 256, 0, stream>>>(src, dst, cur, ssrc, N_EDGES);

    int gblocks = (N_NODES + 3) / 4;
    // layer 0
    gather_k<<<gblocks, 256, 0, stream>>>(x, rowptr, ssrc, tb, N_NODES);
    mlp64_k<<<2048, 256, 0, stream>>>(tb, zb, l0w1, l0b1, l0w2, l0b2, N_NODES, 1);
    // layer 1
    gather_k<<<gblocks, 256, 0, stream>>>(zb, rowptr, ssrc, tb, N_NODES);
    mlp64_k<<<2048, 256, 0, stream>>>(tb, zb, l1w1, l1b1, l1w2, l1b2, N_NODES, 1);
    // layer 2 + log_softmax
    gather_k<<<gblocks, 256, 0, stream>>>(zb, rowptr, ssrc, tb, N_NODES);
    final_k<<<512, 256, 0, stream>>>(tb, out, l2w1, l2b1, l2w2, l2b2, N_NODES);
}

// Round 4
// 447.523 us; speedup vs baseline: 1.6596x; 1.1335x over previous
//
#include <hip/hip_runtime.h>
#include <math.h>

#define N_NODES 100000
#define N_EDGES 1600000
#define C 64
#define OUTC 8
#define SCAN_NBLK ((N_NODES + 255) / 256)  // 391
#define FILL_RANGES 8
#define FILL_BLOCKS 2048  // 256 blocks per range

// ---------- CSR build ----------
__global__ __launch_bounds__(256) void hist_k(const int* __restrict__ dst, int* __restrict__ deg, int ne) {
    int e = blockIdx.x * 256 + threadIdx.x;
    if (e < ne) atomicAdd(&deg[dst[e]], 1);
}

__global__ __launch_bounds__(256) void scan_partial_k(const int* __restrict__ deg, int* __restrict__ part, int n) {
    __shared__ int red[256];
    int t = threadIdx.x;
    int i = blockIdx.x * 256 + t;
    red[t] = (i < n) ? deg[i] : 0;
    __syncthreads();
    for (int off = 128; off > 0; off >>= 1) {
        if (t < off) red[t] += red[t + off];
        __syncthreads();
    }
    if (t == 0) part[blockIdx.x] = red[0];
}

__global__ __launch_bounds__(512) void scan_part2_k(int* __restrict__ part, int nb) {
    __shared__ int sm[512];
    int t = threadIdx.x;
    int v = (t < nb) ? part[t] : 0;
    sm[t] = v;
    __syncthreads();
    for (int off = 1; off < 512; off <<= 1) {
        int u = (t >= off) ? sm[t - off] : 0;
        __syncthreads();
        sm[t] += u;
        __syncthreads();
    }
    if (t < nb) part[t] = sm[t] - v;  // exclusive
}

__global__ __launch_bounds__(256) void scan_final_k(const int* __restrict__ deg, const int* __restrict__ part,
                                                    int* __restrict__ rowptr, int* __restrict__ cur, int n) {
    __shared__ int sm[256];
    int t = threadIdx.x;
    int i = blockIdx.x * 256 + t;
    int v = (i < n) ? deg[i] : 0;
    sm[t] = v;
    __syncthreads();
    for (int off = 1; off < 256; off <<= 1) {
        int u = (t >= off) ? sm[t - off] : 0;
        __syncthreads();
        sm[t] += u;
        __syncthreads();
    }
    int ex = sm[t] - v + part[blockIdx.x];
    if (i < n) { rowptr[i] = ex; cur[i] = ex; }
    if (i == 0) rowptr[n] = N_EDGES;
}

// dst-range-partitioned fill (see R2 note); bucketing pass is the next lever here.
__global__ __launch_bounds__(256) void fill_ranged_k(const int* __restrict__ src, const int* __restrict__ dst,
                                                     int* cur, int* __restrict__ ssrc, int ne) {
    int range = blockIdx.x & (FILL_RANGES - 1);
    int bslot = blockIdx.x >> 3;
    const int nslot = FILL_BLOCKS / FILL_RANGES;  // 256
    int lo = range * (N_NODES / FILL_RANGES);
    int hi = lo + (N_NODES / FILL_RANGES);
    if (range == FILL_RANGES - 1) hi = N_NODES;
    for (int e = bslot * 256 + threadIdx.x; e < ne; e += nslot * 256) {
        int d = dst[e];
        if (d >= lo && d < hi) {
            int p = atomicAdd(&cur[d], 1);
            ssrc[p] = src[e];
        }
    }
}

#define RL(x, l) __uint_as_float(__builtin_amdgcn_readlane(__float_as_uint(x), (l)))

// ---------- fused gather + 64->64->64 MLP, wave per node ----------
// Gather: lane=(slot=lane>>4, chg=lane&15); one dwordx4 load covers 4 neighbor rows.
// After slot-reduce every lane holds t[4*chg..4*chg+3]; MLP k-th input is
// readlane(acc.comp[k&3], k>>2) -- no LDS bridge needed.
__global__ __launch_bounds__(256) void fused_mlp_k(const float* __restrict__ feat,
                                                   const int* __restrict__ rowptr,
                                                   const int* __restrict__ ssrc,
                                                   float* __restrict__ zout,
                                                   const float* __restrict__ W1, const float* __restrict__ b1,
                                                   const float* __restrict__ W2, const float* __restrict__ b2,
                                                   int n, int relu_out) {
    const float4* feat4 = (const float4*)feat;
    int lane = threadIdx.x & 63;
    int slot = lane >> 4;
    int chg  = lane & 15;
    float w1c[64], w2c[64];
#pragma unroll
    for (int k = 0; k < 64; k++) w1c[k] = W1[k * 64 + lane];
#pragma unroll
    for (int k = 0; k < 64; k++) w2c[k] = W2[k * 64 + lane];
    float b1l = b1[lane], b2l = b2[lane];
    int wid = blockIdx.x * 4 + (threadIdx.x >> 6);
    int nw  = gridDim.x * 4;
    for (int nd = wid; nd < n; nd += nw) {
        int beg = rowptr[nd], end = rowptr[nd + 1];
        float4 acc = make_float4(0.f, 0.f, 0.f, 0.f);
        if (slot == 0) acc = feat4[(size_t)nd * 16 + chg];  // fused + x_i
        int e = beg;
        for (; e + 8 <= end; e += 8) {  // 8 edges (2x4) in flight
            int iA = ssrc[e + slot];
            int iB = ssrc[e + 4 + slot];
            float4 vA = feat4[(size_t)iA * 16 + chg];
            float4 vB = feat4[(size_t)iB * 16 + chg];
            acc.x += vA.x + vB.x; acc.y += vA.y + vB.y;
            acc.z += vA.z + vB.z; acc.w += vA.w + vB.w;
        }
        for (; e < end; e += 4) {
            int myE = e + slot;
            if (myE < end) {
                int i = ssrc[myE];
                float4 v = feat4[(size_t)i * 16 + chg];
                acc.x += v.x; acc.y += v.y; acc.z += v.z; acc.w += v.w;
            }
        }
        // reduce the 4 slot groups -> all lanes hold totals for their chg
        acc.x += __shfl_xor(acc.x, 16, 64); acc.y += __shfl_xor(acc.y, 16, 64);
        acc.z += __shfl_xor(acc.z, 16, 64); acc.w += __shfl_xor(acc.w, 16, 64);
        acc.x += __shfl_xor(acc.x, 32, 64); acc.y += __shfl_xor(acc.y, 32, 64);
        acc.z += __shfl_xor(acc.z, 32, 64); acc.w += __shfl_xor(acc.w, 32, 64);
        // layer 1: h = relu(t W1 + b1), lane = output channel; 4-way acc split
        float h0 = 0.f, h1 = 0.f, h2 = 0.f, h3 = 0.f;
#pragma unroll
        for (int q = 0; q < 16; q++) {
            h0 = fmaf(RL(acc.x, q), w1c[4 * q + 0], h0);
            h1 = fmaf(RL(acc.y, q), w1c[4 * q + 1], h1);
            h2 = fmaf(RL(acc.z, q), w1c[4 * q + 2], h2);
            h3 = fmaf(RL(acc.w, q), w1c[4 * q + 3], h3);
        }
        float h = fmaxf(b1l + ((h0 + h1) + (h2 + h3)), 0.f);
        // layer 2: y = h W2 + b2
        float y0 = 0.f, y1 = 0.f, y2 = 0.f, y3 = 0.f;
#pragma unroll
        for (int q = 0; q < 16; q++) {
            y0 = fmaf(RL(h, 4 * q + 0), w2c[4 * q + 0], y0);
            y1 = fmaf(RL(h, 4 * q + 1), w2c[4 * q + 1], y1);
            y2 = fmaf(RL(h, 4 * q + 2), w2c[4 * q + 2], y2);
            y3 = fmaf(RL(h, 4 * q + 3), w2c[4 * q + 3], y3);
        }
        float y = b2l + ((y0 + y1) + (y2 + y3));
        if (relu_out) y = fmaxf(y, 0.f);
        zout[(size_t)nd * C + lane] = y;
    }
}

// ---------- fused gather + 64->8->8 MLP + log_softmax ----------
__global__ __launch_bounds__(256) void fused_final_k(const float* __restrict__ feat,
                                                     const int* __restrict__ rowptr,
                                                     const int* __restrict__ ssrc,
                                                     float* __restrict__ out,
                                                     const float* __restrict__ W1, const float* __restrict__ b1,
                                                     const float* __restrict__ W2, const float* __restrict__ b2,
                                                     int n) {
    const float4* feat4 = (const float4*)feat;
    int lane = threadIdx.x & 63;
    int slot = lane >> 4;
    int chg  = lane & 15;
    int j = lane & 7;   // output channel
    int g = lane >> 3;  // k-slice group (8 groups of 8 input ch)
    float w1r[8], w2r[8];
#pragma unroll
    for (int i = 0; i < 8; i++) w1r[i] = W1[(g * 8 + i) * OUTC + j];
#pragma unroll
    for (int i = 0; i < 8; i++) w2r[i] = W2[i * OUTC + j];
    float b1j = b1[j], b2j = b2[j];
    int wid = blockIdx.x * 4 + (threadIdx.x >> 6);
    int nw  = gridDim.x * 4;
    for (int nd = wid; nd < n; nd += nw) {
        int beg = rowptr[nd], end = rowptr[nd + 1];
        float4 acc = make_float4(0.f, 0.f, 0.f, 0.f);
        if (slot == 0) acc = feat4[(size_t)nd * 16 + chg];
        int e = beg;
        for (; e + 8 <= end; e += 8) {
            int iA = ssrc[e + slot];
            int iB = ssrc[e + 4 + slot];
            float4 vA = feat4[(size_t)iA * 16 + chg];
            float4 vB = feat4[(size_t)iB * 16 + chg];
            acc.x += vA.x + vB.x; acc.y += vA.y + vB.y;
            acc.z += vA.z + vB.z; acc.w += vA.w + vB.w;
        }
        for (; e < end; e += 4) {
            int myE = e + slot;
            if (myE < end) {
                int i = ssrc[myE];
                float4 v = feat4[(size_t)i * 16 + chg];
                acc.x += v.x; acc.y += v.y; acc.z += v.z; acc.w += v.w;
            }
        }
        acc.x += __shfl_xor(acc.x, 16, 64); acc.y += __shfl_xor(acc.y, 16, 64);
        acc.z += __shfl_xor(acc.z, 16, 64); acc.w += __shfl_xor(acc.w, 16, 64);
        acc.x += __shfl_xor(acc.x, 32, 64); acc.y += __shfl_xor(acc.y, 32, 64);
        acc.z += __shfl_xor(acc.z, 32, 64); acc.w += __shfl_xor(acc.w, 32, 64);
        // t[m], m=g*8+i lives in lane m>>2 = g*2+(i>>2), component i&3 (compile-time)
        float h = 0.f;
#pragma unroll
        for (int i = 0; i < 8; i++) {
            float compv = (i & 3) == 0 ? acc.x : (i & 3) == 1 ? acc.y : (i & 3) == 2 ? acc.z : acc.w;
            float tm = __shfl(compv, g * 2 + (i >> 2), 64);
            h = fmaf(tm, w1r[i], h);
        }
        h += __shfl_xor(h, 8, 64);
        h += __shfl_xor(h, 16, 64);
        h += __shfl_xor(h, 32, 64);
        h = fmaxf(h + b1j, 0.f);
        float y = b2j;
#pragma unroll
        for (int k = 0; k < 8; k++) {
            float hk = __shfl(h, (lane & ~7) + k, 64);
            y = fmaf(hk, w2r[k], y);
        }
        float m = y;
        m = fmaxf(m, __shfl_xor(m, 1, 64));
        m = fmaxf(m, __shfl_xor(m, 2, 64));
        m = fmaxf(m, __shfl_xor(m, 4, 64));
        float ex = expf(y - m);
        float ssum = ex;
        ssum += __shfl_xor(ssum, 1, 64);
        ssum += __shfl_xor(ssum, 2, 64);
        ssum += __shfl_xor(ssum, 4, 64);
        float res = (y - m) - logf(ssum);
        if (lane < 8) out[(size_t)nd * OUTC + lane] = res;
    }
}

extern "C" void kernel_launch(void* const* d_in, const int* in_sizes, int n_in,
                              void* d_out, int out_size, void* d_ws, size_t ws_size,
                              hipStream_t stream) {
    const float* x = (const float*)d_in[0];
    const int* ei = (const int*)d_in[1];
    const float* l0w1 = (const float*)d_in[3],  *l0b1 = (const float*)d_in[4];
    const float* l0w2 = (const float*)d_in[5],  *l0b2 = (const float*)d_in[6];
    const float* l1w1 = (const float*)d_in[7],  *l1b1 = (const float*)d_in[8];
    const float* l1w2 = (const float*)d_in[9],  *l1b2 = (const float*)d_in[10];
    const float* l2w1 = (const float*)d_in[11], *l2b1 = (const float*)d_in[12];
    const float* l2w2 = (const float*)d_in[13], *l2b2 = (const float*)d_in[14];
    float* out = (float*)d_out;
    const int* src = ei;
    const int* dst = ei + N_EDGES;

    char* ws = (char*)d_ws;
    size_t off = 0;
    auto carve = [&](size_t bytes) -> void* {
        void* p = ws + off;
        off += (bytes + 255) & ~(size_t)255;
        return p;
    };
    int* deg    = (int*)carve((size_t)N_NODES * 4);
    int* rowptr = (int*)carve((size_t)(N_NODES + 1) * 4);
    int* cur    = (int*)carve((size_t)N_NODES * 4);
    int* part   = (int*)carve((size_t)SCAN_NBLK * 4);
    int* ssrc   = (int*)carve((size_t)N_EDGES * 4);
    float* tb   = (float*)carve((size_t)N_NODES * C * 4);
    float* zb   = (float*)carve((size_t)N_NODES * C * 4);
    (void)ws_size;

    // CSR build
    hipMemsetAsync(deg, 0, (size_t)N_NODES * 4, stream);
    hist_k<<<(N_EDGES + 255) / 256, 256, 0, stream>>>(dst, deg, N_EDGES);
    scan_partial_k<<<SCAN_NBLK, 256, 0, stream>>>(deg, part, N_NODES);
    scan_part2_k<<<1, 512, 0, stream>>>(part, SCAN_NBLK);
    scan_final_k<<<SCAN_NBLK, 256, 0, stream>>>(deg, part, rowptr, cur, N_NODES);
    fill_ranged_k<<<FILL_BLOCKS, 256, 0, stream>>>(src, dst, cur, ssrc, N_EDGES);

    // fused layers
    fused_mlp_k<<<4096, 256, 0, stream>>>(x,  rowptr, ssrc, zb, l0w1, l0b1, l0w2, l0b2, N_NODES, 1);
    fused_mlp_k<<<4096, 256, 0, stream>>>(zb, rowptr, ssrc, tb, l1w1, l1b1, l1w2, l1b2, N_NODES, 1);
    fused_final_k<<<2048, 256, 0, stream>>>(tb, rowptr, ssrc, out, l2w1, l2b1, l2w2, l2b2, N_NODES);
}

// Round 5
// 430.257 us; speedup vs baseline: 1.7262x; 1.0401x over previous
//
#include <hip/hip_runtime.h>
#include <math.h>

#define N_NODES 100000
#define N_EDGES 1600000
#define C 64
#define OUTC 8
#define SCAN_NBLK ((N_NODES + 255) / 256)  // 391
#define FILL_RANGES 8
#define FILL_BLOCKS 2048  // 256 blocks per range

// bf16 helpers (storage-only precision cut; all math in f32)
__device__ __forceinline__ float bflo(unsigned u) { return __uint_as_float(u << 16); }
__device__ __forceinline__ float bfhi(unsigned u) { return __uint_as_float(u & 0xFFFF0000u); }
__device__ __forceinline__ unsigned short f2bf(float f) {  // RNE
    unsigned b = __float_as_uint(f);
    b += 0x7FFFu + ((b >> 16) & 1u);
    return (unsigned short)(b >> 16);
}

// ---------- CSR build ----------
__global__ __launch_bounds__(256) void hist_k(const int* __restrict__ dst, int* __restrict__ deg, int ne) {
    int e = blockIdx.x * 256 + threadIdx.x;
    if (e < ne) atomicAdd(&deg[__builtin_nontemporal_load(dst + e)], 1);
}

__global__ __launch_bounds__(256) void scan_partial_k(const int* __restrict__ deg, int* __restrict__ part, int n) {
    __shared__ int red[256];
    int t = threadIdx.x;
    int i = blockIdx.x * 256 + t;
    red[t] = (i < n) ? deg[i] : 0;
    __syncthreads();
    for (int off = 128; off > 0; off >>= 1) {
        if (t < off) red[t] += red[t + off];
        __syncthreads();
    }
    if (t == 0) part[blockIdx.x] = red[0];
}

__global__ __launch_bounds__(512) void scan_part2_k(int* __restrict__ part, int nb) {
    __shared__ int sm[512];
    int t = threadIdx.x;
    int v = (t < nb) ? part[t] : 0;
    sm[t] = v;
    __syncthreads();
    for (int off = 1; off < 512; off <<= 1) {
        int u = (t >= off) ? sm[t - off] : 0;
        __syncthreads();
        sm[t] += u;
        __syncthreads();
    }
    if (t < nb) part[t] = sm[t] - v;  // exclusive
}

__global__ __launch_bounds__(256) void scan_final_k(const int* __restrict__ deg, const int* __restrict__ part,
                                                    int* __restrict__ rowptr, int* __restrict__ cur, int n) {
    __shared__ int sm[256];
    int t = threadIdx.x;
    int i = blockIdx.x * 256 + t;
    int v = (i < n) ? deg[i] : 0;
    sm[t] = v;
    __syncthreads();
    for (int off = 1; off < 256; off <<= 1) {
        int u = (t >= off) ? sm[t - off] : 0;
        __syncthreads();
        sm[t] += u;
        __syncthreads();
    }
    int ex = sm[t] - v + part[blockIdx.x];
    if (i < n) { rowptr[i] = ex; cur[i] = ex; }
    if (i == 0) rowptr[n] = N_EDGES;
}

// ranged fill; nt-loads keep the streaming src/dst out of L2 so the ~800KB
// per-XCD ssrc slice stays resident and lines fill completely before writeback.
__global__ __launch_bounds__(256) void fill_ranged_k(const int* __restrict__ src, const int* __restrict__ dst,
                                                     int* cur, int* __restrict__ ssrc, int ne) {
    int range = blockIdx.x & (FILL_RANGES - 1);
    int bslot = blockIdx.x >> 3;
    const int nslot = FILL_BLOCKS / FILL_RANGES;  // 256
    int lo = range * (N_NODES / FILL_RANGES);
    int hi = lo + (N_NODES / FILL_RANGES);
    if (range == FILL_RANGES - 1) hi = N_NODES;
    for (int e = bslot * 256 + threadIdx.x; e < ne; e += nslot * 256) {
        int d = __builtin_nontemporal_load(dst + e);
        if (d >= lo && d < hi) {
            int p = atomicAdd(&cur[d], 1);
            ssrc[p] = __builtin_nontemporal_load(src + e);
        }
    }
}

// ---------- f32 -> bf16 feature conversion (once) ----------
__global__ __launch_bounds__(256) void conv_bf16_k(const float* __restrict__ in, unsigned short* __restrict__ outb, int nElem) {
    int i = blockIdx.x * 256 + threadIdx.x;
    int stride = gridDim.x * 256;
    for (int e = i * 4; e < nElem; e += stride * 4) {
        float4 v = *(const float4*)(in + e);
        ushort4 o;
        o.x = f2bf(v.x); o.y = f2bf(v.y); o.z = f2bf(v.z); o.w = f2bf(v.w);
        *(ushort4*)(outb + e) = o;
    }
}

// ---------- aggregation from bf16 rows: t[i] = x_i + sum_{j->i} x_j (f32 out) ----------
// lane = (slot=lane>>4, chg=lane&15); one uint2 load = 4 bf16 channels; 4 edges/instr.
__global__ __launch_bounds__(256) void gather_bf16_k(const unsigned short* __restrict__ featb,
                                                     const int* __restrict__ rowptr,
                                                     const int* __restrict__ ssrc,
                                                     float* __restrict__ tout, int n) {
    const uint2* feat2 = (const uint2*)featb;  // row = 16 uint2 (128B)
    int lane = threadIdx.x & 63;
    int slot = lane >> 4;
    int chg  = lane & 15;
    int wid = blockIdx.x * 4 + (threadIdx.x >> 6);
    if (wid >= n) return;
    int beg = rowptr[wid], end = rowptr[wid + 1];
    float ax = 0.f, ay = 0.f, az = 0.f, aw = 0.f;
    if (slot == 0) {  // fused + x_i
        uint2 v = feat2[(size_t)wid * 16 + chg];
        ax = bflo(v.x); ay = bfhi(v.x); az = bflo(v.y); aw = bfhi(v.y);
    }
    int e = beg;
    for (; e + 8 <= end; e += 8) {  // 8 edges (2 groups of 4) in flight
        int iA = ssrc[e + slot];
        int iB = ssrc[e + 4 + slot];
        uint2 vA = feat2[(size_t)iA * 16 + chg];
        uint2 vB = feat2[(size_t)iB * 16 + chg];
        ax += bflo(vA.x) + bflo(vB.x);
        ay += bfhi(vA.x) + bfhi(vB.x);
        az += bflo(vA.y) + bflo(vB.y);
        aw += bfhi(vA.y) + bfhi(vB.y);
    }
    for (; e < end; e += 4) {
        int myE = e + slot;
        if (myE < end) {
            int i = ssrc[myE];
            uint2 v = feat2[(size_t)i * 16 + chg];
            ax += bflo(v.x); ay += bfhi(v.x); az += bflo(v.y); aw += bfhi(v.y);
        }
    }
    // reduce the 4 slot groups
    ax += __shfl_xor(ax, 16, 64); ay += __shfl_xor(ay, 16, 64);
    az += __shfl_xor(az, 16, 64); aw += __shfl_xor(aw, 16, 64);
    ax += __shfl_xor(ax, 32, 64); ay += __shfl_xor(ay, 32, 64);
    az += __shfl_xor(az, 32, 64); aw += __shfl_xor(aw, 32, 64);
    if (slot == 0) ((float4*)tout)[(size_t)wid * 16 + chg] = make_float4(ax, ay, az, aw);
}

#define RL(x, l) __uint_as_float(__builtin_amdgcn_readlane(__float_as_uint(x), (l)))

// ---------- 64->64->64 MLP, wave per node, weights in VGPRs (no spill: lb 256,2) ----------
__global__ __launch_bounds__(256, 2) void mlp64_k(const float* __restrict__ tin,
                                                  unsigned short* __restrict__ zoutb,
                                                  const float* __restrict__ W1, const float* __restrict__ b1,
                                                  const float* __restrict__ W2, const float* __restrict__ b2,
                                                  int n, int relu_out) {
    int lane = threadIdx.x & 63;
    float w1c[64], w2c[64];
#pragma unroll
    for (int k = 0; k < 64; k++) w1c[k] = W1[k * 64 + lane];
#pragma unroll
    for (int k = 0; k < 64; k++) w2c[k] = W2[k * 64 + lane];
    float b1l = b1[lane], b2l = b2[lane];
    int wid = blockIdx.x * 4 + (threadIdx.x >> 6);
    int nw = gridDim.x * 4;
    for (int nd = wid; nd < n; nd += nw) {
        float tv = tin[(size_t)nd * C + lane];
        float h0 = 0.f, h1 = 0.f, h2 = 0.f, h3 = 0.f;
#pragma unroll
        for (int q = 0; q < 16; q++) {
            h0 = fmaf(RL(tv, 4 * q + 0), w1c[4 * q + 0], h0);
            h1 = fmaf(RL(tv, 4 * q + 1), w1c[4 * q + 1], h1);
            h2 = fmaf(RL(tv, 4 * q + 2), w1c[4 * q + 2], h2);
            h3 = fmaf(RL(tv, 4 * q + 3), w1c[4 * q + 3], h3);
        }
        float h = fmaxf(b1l + ((h0 + h1) + (h2 + h3)), 0.f);
        float y0 = 0.f, y1 = 0.f, y2 = 0.f, y3 = 0.f;
#pragma unroll
        for (int q = 0; q < 16; q++) {
            y0 = fmaf(RL(h, 4 * q + 0), w2c[4 * q + 0], y0);
            y1 = fmaf(RL(h, 4 * q + 1), w2c[4 * q + 1], y1);
            y2 = fmaf(RL(h, 4 * q + 2), w2c[4 * q + 2], y2);
            y3 = fmaf(RL(h, 4 * q + 3), w2c[4 * q + 3], y3);
        }
        float y = b2l + ((y0 + y1) + (y2 + y3));
        if (relu_out) y = fmaxf(y, 0.f);
        zoutb[(size_t)nd * C + lane] = f2bf(y);
    }
}

// ---------- final 64->8->8 MLP + log_softmax (reads f32 t) ----------
__global__ __launch_bounds__(256) void final_k(const float* __restrict__ tin,
                                               float* __restrict__ out,
                                               const float* __restrict__ W1, const float* __restrict__ b1,
                                               const float* __restrict__ W2, const float* __restrict__ b2,
                                               int n) {
    int lane = threadIdx.x & 63;
    int j = lane & 7;   // output channel
    int g = lane >> 3;  // k-slice group
    float w1r[8], w2r[8];
#pragma unroll
    for (int i = 0; i < 8; i++) w1r[i] = W1[(g * 8 + i) * OUTC + j];
#pragma unroll
    for (int i = 0; i < 8; i++) w2r[i] = W2[i * OUTC + j];
    float b1j = b1[j], b2j = b2[j];
    int wid = blockIdx.x * 4 + (threadIdx.x >> 6);
    int nw = gridDim.x * 4;
    for (int nd = wid; nd < n; nd += nw) {
        float tv = tin[(size_t)nd * C + lane];
        float h = 0.f;
#pragma unroll
        for (int i = 0; i < 8; i++) {
            float tk = __shfl(tv, g * 8 + i, 64);
            h = fmaf(tk, w1r[i], h);
        }
        h += __shfl_xor(h, 8, 64);
        h += __shfl_xor(h, 16, 64);
        h += __shfl_xor(h, 32, 64);
        h = fmaxf(h + b1j, 0.f);
        float y = b2j;
#pragma unroll
        for (int k = 0; k < 8; k++) {
            float hk = __shfl(h, (lane & ~7) + k, 64);
            y = fmaf(hk, w2r[k], y);
        }
        float m = y;
        m = fmaxf(m, __shfl_xor(m, 1, 64));
        m = fmaxf(m, __shfl_xor(m, 2, 64));
        m = fmaxf(m, __shfl_xor(m, 4, 64));
        float ex = expf(y - m);
        float ssum = ex;
        ssum += __shfl_xor(ssum, 1, 64);
        ssum += __shfl_xor(ssum, 2, 64);
        ssum += __shfl_xor(ssum, 4, 64);
        float res = (y - m) - logf(ssum);
        if (lane < 8) out[(size_t)nd * OUTC + lane] = res;
    }
}

extern "C" void kernel_launch(void* const* d_in, const int* in_sizes, int n_in,
                              void* d_out, int out_size, void* d_ws, size_t ws_size,
                              hipStream_t stream) {
    const float* x = (const float*)d_in[0];
    const int* ei = (const int*)d_in[1];
    const float* l0w1 = (const float*)d_in[3],  *l0b1 = (const float*)d_in[4];
    const float* l0w2 = (const float*)d_in[5],  *l0b2 = (const float*)d_in[6];
    const float* l1w1 = (const float*)d_in[7],  *l1b1 = (const float*)d_in[8];
    const float* l1w2 = (const float*)d_in[9],  *l1b2 = (const float*)d_in[10];
    const float* l2w1 = (const float*)d_in[11], *l2b1 = (const float*)d_in[12];
    const float* l2w2 = (const float*)d_in[13], *l2b2 = (const float*)d_in[14];
    float* out = (float*)d_out;
    const int* src = ei;
    const int* dst = ei + N_EDGES;

    char* ws = (char*)d_ws;
    size_t off = 0;
    auto carve = [&](size_t bytes) -> void* {
        void* p = ws + off;
        off += (bytes + 255) & ~(size_t)255;
        return p;
    };
    int* deg    = (int*)carve((size_t)N_NODES * 4);
    int* rowptr = (int*)carve((size_t)(N_NODES + 1) * 4);
    int* cur    = (int*)carve((size_t)N_NODES * 4);
    int* part   = (int*)carve((size_t)SCAN_NBLK * 4);
    int* ssrc   = (int*)carve((size_t)N_EDGES * 4);
    unsigned short* xb = (unsigned short*)carve((size_t)N_NODES * C * 2);
    unsigned short* zb = (unsigned short*)carve((size_t)N_NODES * C * 2);
    float* tb   = (float*)carve((size_t)N_NODES * C * 4);
    (void)ws_size;

    // CSR build
    hipMemsetAsync(deg, 0, (size_t)N_NODES * 4, stream);
    hist_k<<<(N_EDGES + 255) / 256, 256, 0, stream>>>(dst, deg, N_EDGES);
    scan_partial_k<<<SCAN_NBLK, 256, 0, stream>>>(deg, part, N_NODES);
    scan_part2_k<<<1, 512, 0, stream>>>(part, SCAN_NBLK);
    scan_final_k<<<SCAN_NBLK, 256, 0, stream>>>(deg, part, rowptr, cur, N_NODES);
    fill_ranged_k<<<FILL_BLOCKS, 256, 0, stream>>>(src, dst, cur, ssrc, N_EDGES);

    // features -> bf16 (storage only)
    conv_bf16_k<<<2048, 256, 0, stream>>>(x, xb, N_NODES * C);

    int gblocks = (N_NODES + 3) / 4;
    // layer 0
    gather_bf16_k<<<gblocks, 256, 0, stream>>>(xb, rowptr, ssrc, tb, N_NODES);
    mlp64_k<<<2048, 256, 0, stream>>>(tb, zb, l0w1, l0b1, l0w2, l0b2, N_NODES, 1);
    // layer 1 (zb consumed into tb before being overwritten)
    gather_bf16_k<<<gblocks, 256, 0, stream>>>(zb, rowptr, ssrc, tb, N_NODES);
    mlp64_k<<<2048, 256, 0, stream>>>(tb, zb, l1w1, l1b1, l1w2, l1b2, N_NODES, 1);
    // layer 2 + log_softmax
    gather_bf16_k<<<gblocks, 256, 0, stream>>>(zb, rowptr, ssrc, tb, N_NODES);
    final_k<<<512, 256, 0, stream>>>(tb, out, l2w1, l2b1, l2w2, l2b2, N_NODES);
}